// Round 11
// baseline (449.301 us; speedup 1.0000x reference)
//
#include <hip/hip_runtime.h>
#include <math.h>

// EntNet forward on MI355X.
// Sizes: VOC=32000, MEM=128, NSLOTS=20, NSENT=128, MAXLEN=32, QLEN=16, ANSLEN=8, B=64
//
// R11 structure (from R10's 5200 cyc/step post-mortem: cost = serialized phases,
// scattered C-layout writes, cross-wave gate->g_l->update dependency):
//  (1) MFMA operand swap: C[n][b] = W x U^T (A=weight frag, B=state frag; both
//      operands share the (row,k) fragment layout so only the argument order
//      changes). Lane owns ONE b-column + 16 n-rows in 4 contiguous quads ->
//      state writes 4xb64, wsv 4xdwordx4, h_out 4xfloat4, ONE g value per lane.
//  (2) gate = diag(S_t U^T) via 8 extra MFMAs REUSING the state fragments;
//      s in bf16 from prep (sTb16). Diag extracted lane-locally (15-cndmask
//      tree + shfl_xor(32)) -> no g_l, no cross-wave gate dependency.
//  (3) ping-pong state + wred -> ONE barrier per step.
// Register model (R2/3/4/8): budget = 512/(waves/SIMD) incl. AGPRs; 512thr
// 1blk -> 256/wave. This kernel ~144 array VGPRs + 48 AGPR + temps < 256.
// Spill tripwire: WRITE_SIZE (~640KB clean; MBs = scratch).

typedef __attribute__((ext_vector_type(8)))  short bf16x8;
typedef __attribute__((ext_vector_type(16))) float f32x16;

__device__ __forceinline__ unsigned short f2bh(float x) {   // f32 -> bf16 RNE
    unsigned int u = __float_as_uint(x);
    u += 0x7FFFu + ((u >> 16) & 1u);
    return (unsigned short)(u >> 16);
}
__device__ __forceinline__ float bh2f(unsigned short h) {
    return __uint_as_float(((unsigned int)h) << 16);
}

// ---------------------------------------------------------------- prep
__global__ __launch_bounds__(128) void prep_kernel(
    const int* __restrict__ ids, const int* __restrict__ ques, const int* __restrict__ ans,
    const float* __restrict__ E, const float* __restrict__ Ww, const float* __restrict__ Wb,
    const float* __restrict__ Vw, const float* __restrict__ Vb, const float* __restrict__ skeys,
    unsigned short* __restrict__ sTb16, float* __restrict__ WsT, float* __restrict__ vkey,
    float* __restrict__ qv, float* __restrict__ a1v, float* __restrict__ a2v,
    float* __restrict__ SK)
{
    const int bi  = blockIdx.x;
    const int tid = threadIdx.x;   // 128
    __shared__ float s_l[8][132];
    __shared__ float sk_l[20 * 132];
    __shared__ float k_l[128];
    if (bi < 1024) {
        const int b = bi >> 4;
        const int g = bi & 15;
        for (int r = tid; r < 2560; r += 128) sk_l[(r >> 7) * 132 + (r & 127)] = skeys[r];
        for (int tt = 0; tt < 8; ++tt) {
            const int t     = g * 8 + tt;
            const int token = ids[b * 4096 + t];
            const float v   = E[token * 128 + tid];
            s_l[tt][tid] = v;
            sTb16[(t * 64 + b) * 128 + tid] = f2bh(v);   // bf16 plane, layout (t,b,m)
        }
        __syncthreads();
        // Ws rows
        float acc[8];
        const float wbn = Wb[tid];
        #pragma unroll
        for (int i = 0; i < 8; ++i) acc[i] = wbn;
        const float4* wrow = (const float4*)(Ww + tid * 128);
        for (int m4 = 0; m4 < 32; ++m4) {
            const float4 w = wrow[m4];
            #pragma unroll
            for (int tt = 0; tt < 8; ++tt) {
                acc[tt] += s_l[tt][m4*4+0]*w.x + s_l[tt][m4*4+1]*w.y
                         + s_l[tt][m4*4+2]*w.z + s_l[tt][m4*4+3]*w.w;
            }
        }
        for (int tt = 0; tt < 8; ++tt)
            WsT[((g*8+tt) * 64 + b) * 128 + tid] = acc[tt];     // layout (t, b, n)
        // SK[j][t][b] = dot(s_t[b], skeys[j])  (gate key-dot, hoisted from scan)
        for (int idx = tid; idx < 160; idx += 128) {
            const int tt = idx / 20;
            const int jj = idx - tt * 20;
            float d = 0.f;
            for (int m = 0; m < 128; ++m) d += s_l[tt][m] * sk_l[jj * 132 + m];
            SK[(jj * 128 + (g*8 + tt)) * 64 + b] = d;
        }
    } else if (bi < 1044) {
        const int j = bi - 1024;
        k_l[tid] = skeys[j * 128 + tid];
        __syncthreads();
        float acc = Vb[tid];
        const float4* vrow = (const float4*)(Vw + tid * 128);
        for (int m4 = 0; m4 < 32; ++m4) {
            const float4 w = vrow[m4];
            acc += k_l[m4*4]*w.x + k_l[m4*4+1]*w.y + k_l[m4*4+2]*w.z + k_l[m4*4+3]*w.w;
        }
        vkey[j * 128 + tid] = acc;
    } else {
        const int b = bi - 1044;
        float sq = 0.f, s1 = 0.f, s2 = 0.f;
        for (int i = 0; i < 16; ++i) sq += E[ques[b*16+i] * 128 + tid];
        for (int i = 0; i < 8;  ++i) s1 += E[ans[(b*8+i)*2+0] * 128 + tid];
        for (int i = 0; i < 8;  ++i) s2 += E[ans[(b*8+i)*2+1] * 128 + tid];
        qv [b*128+tid] = sq * (1.f/16.f);
        a1v[b*128+tid] = s1 * 0.125f;
        a2v[b*128+tid] = s2 * 0.125f;
    }
}

// ---------------------------------------------------------------- scan
// One block per slot j. 512 threads = 8 waves, 2 waves/SIMD.
// Wave = (bt2 = wave&1 b-tile, nt2 = wave>>1 n-tile). Owned C tile: C[n][b],
// n in nt2*32..+31, b in bt2*32..+31. Lane (l32, q): column b = bt2*32+l32,
// rows n(r) = nt2*32 + (r&3) + 8*(r>>2) + 4q  [C/D layout, m74/m101].
// State AB (bf16 [64][136], ping-pong): B-operand frag row = b, read as b128.
// Weights w_h/w_l (hi/lo bf16 of Uw rows nw = nt2*32+l32) = A operand, 64 VGPRs.
// Gate: gacc = S_t x U^T diag tile via 8 MFMAs (A = s-frag from sTb16, B = same
// state frags); diag -> per-lane g[b]; sigmoid(inv_s*d + SK).
// fp32 recurrence xprev[16] in regs; state plane rounded bf16 (R10-proven).
// ONE barrier per step.
__global__ __launch_bounds__(512, 1) void scan_kernel(
    const unsigned short* __restrict__ sTb16, const float* __restrict__ WsT,
    const float* __restrict__ vkey, const float* __restrict__ Uw,
    const float* __restrict__ Ub, const float* __restrict__ SK,
    float* __restrict__ h_out)
{
    __shared__ unsigned short AB[2][64 * 136];     // bf16 state, ping-pong
    __shared__ __align__(16) float wred[2][8];     // per-wave ssq, ping-pong

    const int j    = blockIdx.x;
    const int tid  = threadIdx.x;        // 512
    const int wave = tid >> 6;           // 0..7
    const int lane = tid & 63;
    const int l32  = lane & 31;
    const int q    = lane >> 5;          // 0..1
    const int bt2  = wave & 1;           // b tile
    const int nt2  = wave >> 1;          // n tile
    const int b    = bt2 * 32 + l32;     // owned batch column
    const int nw   = nt2 * 32 + l32;     // weight fragment row

    // ---- one-time: weight fragments (A operand) -> 64 VGPRs ----
    bf16x8 w_h[8], w_l[8];
    #pragma unroll
    for (int kc = 0; kc < 8; ++kc) {
        const float4* src = (const float4*)(Uw + nw*128 + kc*16 + q*8);
        const float4 v0 = src[0], v1 = src[1];
        const float xs[8] = {v0.x,v0.y,v0.z,v0.w, v1.x,v1.y,v1.z,v1.w};
        #pragma unroll
        for (int e = 0; e < 8; ++e) {
            const unsigned short h = f2bh(xs[e]);
            w_h[kc][e] = (short)h;
            w_l[kc][e] = (short)f2bh(xs[e] - bh2f(h));
        }
    }
    // ubv[r] = Ub[n(r)] + Vkey[j][n(r)] for the 16 owned rows
    float ubv[16];
    #pragma unroll
    for (int r = 0; r < 16; ++r) {
        const int n = nt2*32 + (r & 3) + 8*(r >> 2) + 4*q;
        ubv[r] = Ub[n] + vkey[j*128 + n];
    }
    for (int i = tid; i < 64*136; i += 512) AB[0][i] = 0;
    if (tid < 8) wred[0][tid] = 0.125f;   // sum = 1 -> inv_s = 1 (state = 0)

    float xprev[16];
    #pragma unroll
    for (int r = 0; r < 16; ++r) xprev[r] = 0.f;

    // ---- step-0 globals ----
    float  wsv[16];
    bf16x8 sfr[8];
    float  skv;
    {
        const float* wp = WsT + (0*64 + b)*128;
        #pragma unroll
        for (int g4 = 0; g4 < 4; ++g4) {
            const float4 w = *(const float4*)(wp + nt2*32 + 8*g4 + 4*q);
            wsv[g4*4+0]=w.x; wsv[g4*4+1]=w.y; wsv[g4*4+2]=w.z; wsv[g4*4+3]=w.w;
        }
        const unsigned short* sp = sTb16 + (0*64 + b)*128;
        #pragma unroll
        for (int kc = 0; kc < 8; ++kc) sfr[kc] = *(const bf16x8*)(sp + kc*16 + q*8);
        skv = SK[(j*128 + 0)*64 + b];
    }
    __syncthreads();

    for (int t = 0; t < 128; ++t) {
        const int cur = t & 1, nxt = cur ^ 1;

        // ---- inv_s from previous step's ssq ----
        const float4 r0 = *(const float4*)(&wred[cur][0]);
        const float4 r1 = *(const float4*)(&wred[cur][4]);
        const float inv_s = 1.f / sqrtf(r0.x+r0.y+r0.z+r0.w + r1.x+r1.y+r1.z+r1.w);

        // ---- state fragments (B operand; shared by main + gate MFMA) ----
        const unsigned short* arow = &AB[cur][b*136 + q*8];
        bf16x8 a[8];
        #pragma unroll
        for (int kc = 0; kc < 8; ++kc) a[kc] = *(const bf16x8*)(arow + kc*16);

        // ---- MFMAs: main C[n][b] (2 planes, 2 chains) + gate diag tile ----
        f32x16 acc0 = {0.f,0.f,0.f,0.f,0.f,0.f,0.f,0.f,
                       0.f,0.f,0.f,0.f,0.f,0.f,0.f,0.f};
        f32x16 acc1 = acc0, gacc = acc0;
        #pragma unroll
        for (int kc = 0; kc < 8; ++kc) {
            gacc = __builtin_amdgcn_mfma_f32_32x32x16_bf16(sfr[kc], a[kc], gacc, 0, 0, 0);
            if (kc & 1) {
                acc1 = __builtin_amdgcn_mfma_f32_32x32x16_bf16(w_h[kc], a[kc], acc1, 0, 0, 0);
                acc1 = __builtin_amdgcn_mfma_f32_32x32x16_bf16(w_l[kc], a[kc], acc1, 0, 0, 0);
            } else {
                acc0 = __builtin_amdgcn_mfma_f32_32x32x16_bf16(w_h[kc], a[kc], acc0, 0, 0, 0);
                acc0 = __builtin_amdgcn_mfma_f32_32x32x16_bf16(w_l[kc], a[kc], acc0, 0, 0, 0);
            }
        }

        // ---- gate: d1[b] = diag element. reg r holds row (r&3)+8*(r>>2)+4q;
        //      diag for col l32 is reg rs=(l32&3)+4*(l32>>3) in half q*=(l32>>2)&1.
        float gg;
        {
            const int rs = (l32 & 3) + 4*(l32 >> 3);
            const float c0 = (rs & 1) ? gacc[1]  : gacc[0];
            const float c1 = (rs & 1) ? gacc[3]  : gacc[2];
            const float c2 = (rs & 1) ? gacc[5]  : gacc[4];
            const float c3 = (rs & 1) ? gacc[7]  : gacc[6];
            const float c4 = (rs & 1) ? gacc[9]  : gacc[8];
            const float c5 = (rs & 1) ? gacc[11] : gacc[10];
            const float c6 = (rs & 1) ? gacc[13] : gacc[12];
            const float c7 = (rs & 1) ? gacc[15] : gacc[14];
            const float d0 = (rs & 2) ? c1 : c0;
            const float d1 = (rs & 2) ? c3 : c2;
            const float d2 = (rs & 2) ? c5 : c4;
            const float d3 = (rs & 2) ? c7 : c6;
            const float e0 = (rs & 4) ? d1 : d0;
            const float e1 = (rs & 4) ? d3 : d2;
            const float v  = (rs & 8) ? e1 : e0;
            const float vo = __shfl_xor(v, 32, 64);
            const float dg = (q == ((l32 >> 2) & 1)) ? v : vo;
            gg = 1.f / (1.f + expf(-(inv_s * dg + skv)));
        }

        // ---- update owned column: 4 quads of contiguous n ----
        unsigned short* wrow = &AB[nxt][b*136];
        float ssq = 0.f;
        #pragma unroll
        for (int g4 = 0; g4 < 4; ++g4) {
            float xs[4];
            #pragma unroll
            for (int e = 0; e < 4; ++e) {
                const int r = g4*4 + e;
                float hr = fmaf(inv_s, acc0[r] + acc1[r], ubv[r] + wsv[r]);
                hr = fmaxf(hr, 0.f);                       // h_cand
                const float x = fmaf(inv_s, xprev[r], gg * hr);
                xprev[r] = x;
                xs[e] = x;
                ssq = fmaf(x, x, ssq);
            }
            const unsigned int p0 = ((unsigned int)f2bh(xs[1]) << 16) | f2bh(xs[0]);
            const unsigned int p1 = ((unsigned int)f2bh(xs[3]) << 16) | f2bh(xs[2]);
            *(uint2*)(wrow + nt2*32 + 8*g4 + 4*q) = make_uint2(p0, p1);
        }

        // ---- prefetch t+1 globals (overlap shuffles + barrier) ----
        {
            const int tn = (t < 127) ? t + 1 : 127;
            const float* wp = WsT + (tn*64 + b)*128;
            #pragma unroll
            for (int g4 = 0; g4 < 4; ++g4) {
                const float4 w = *(const float4*)(wp + nt2*32 + 8*g4 + 4*q);
                wsv[g4*4+0]=w.x; wsv[g4*4+1]=w.y; wsv[g4*4+2]=w.z; wsv[g4*4+3]=w.w;
            }
            const unsigned short* sp = sTb16 + (tn*64 + b)*128;
            #pragma unroll
            for (int kc = 0; kc < 8; ++kc) sfr[kc] = *(const bf16x8*)(sp + kc*16 + q*8);
            skv = SK[(j*128 + tn)*64 + b];
        }

        // ---- block ssq -> wred[nxt] ----
        #pragma unroll
        for (int m = 1; m < 64; m <<= 1) ssq += __shfl_xor(ssq, m, 64);
        if (lane == 0) wred[nxt][wave] = ssq;
        __syncthreads();   // single barrier: AB[nxt] + wred[nxt] published
    }

    // ---- h = inv * state (fp32 path), layout (b, j, m) ----
    const float4 f0 = *(const float4*)(&wred[0][0]);
    const float4 f1 = *(const float4*)(&wred[0][4]);
    const float invf = 1.f / sqrtf(f0.x+f0.y+f0.z+f0.w + f1.x+f1.y+f1.z+f1.w);
    #pragma unroll
    for (int g4 = 0; g4 < 4; ++g4) {
        const float4 o = make_float4(invf*xprev[g4*4+0], invf*xprev[g4*4+1],
                                     invf*xprev[g4*4+2], invf*xprev[g4*4+3]);
        *(float4*)(h_out + (b*20 + j)*128 + nt2*32 + 8*g4 + 4*q) = o;
    }
}

// ---------------------------------------------------------------- final
__global__ __launch_bounds__(128) void final_kernel(
    const float* __restrict__ h, const float* __restrict__ qv,
    const float* __restrict__ a1v, const float* __restrict__ a2v,
    const float* __restrict__ Hw, const float* __restrict__ Hb,
    float* __restrict__ out)
{
    const int b   = blockIdx.x;
    const int tid = threadIdx.x;    // 128
    __shared__ float hb[20][128];
    __shared__ float ql[128];
    __shared__ float ul[128];
    __shared__ float pl[20];
    __shared__ float lgt[20];
    __shared__ float red1[2], red2[2];

    for (int jj = 0; jj < 20; ++jj) hb[jj][tid] = h[(b*20+jj)*128 + tid];
    ql[tid] = qv[b*128 + tid];
    __syncthreads();
    if (tid < 20) {
        float d = 0.f;
        for (int m = 0; m < 128; ++m) d += hb[tid][m] * ql[m];
        lgt[tid] = d;
    }
    __syncthreads();
    if (tid == 0) {
        float mx = lgt[0];
        for (int jj = 1; jj < 20; ++jj) mx = fmaxf(mx, lgt[jj]);
        float s = 0.f;
        for (int jj = 0; jj < 20; ++jj) { const float e = expf(lgt[jj]-mx); pl[jj] = e; s += e; }
        const float is = 1.f / s;
        for (int jj = 0; jj < 20; ++jj) pl[jj] *= is;
    }
    __syncthreads();
    float u = 0.f;
    for (int jj = 0; jj < 20; ++jj) u += pl[jj] * hb[jj][tid];
    ul[tid] = u;
    __syncthreads();
    float acc = ql[tid] + Hb[tid];
    const float4* hwr = (const float4*)(Hw + tid*128);
    for (int m4 = 0; m4 < 32; ++m4) {
        const float4 w = hwr[m4];
        acc += ul[m4*4]*w.x + ul[m4*4+1]*w.y + ul[m4*4+2]*w.z + ul[m4*4+3]*w.w;
    }
    const float r  = fmaxf(acc, 0.f);
    float y1 = r * a1v[b*128+tid];
    float y2 = r * a2v[b*128+tid];
    #pragma unroll
    for (int mask = 1; mask < 64; mask <<= 1) {
        y1 += __shfl_xor(y1, mask, 64);
        y2 += __shfl_xor(y2, mask, 64);
    }
    if ((tid & 63) == 0) { red1[tid>>6] = y1; red2[tid>>6] = y2; }
    __syncthreads();
    if (tid == 0) {
        const float z1 = red1[0] + red1[1];
        const float z2 = red2[0] + red2[1];
        const float mx = fmaxf(z1, z2);
        const float e1 = expf(z1-mx), e2 = expf(z2-mx);
        const float s  = e1 + e2;
        out[b*2+0] = e1 / s;
        out[b*2+1] = e2 / s;
    }
}

// ---------------------------------------------------------------- launch
extern "C" void kernel_launch(void* const* d_in, const int* in_sizes, int n_in,
                              void* d_out, int out_size, void* d_ws, size_t ws_size,
                              hipStream_t stream)
{
    const int*   ids  = (const int*)  d_in[0];
    const int*   ques = (const int*)  d_in[1];
    const int*   ans  = (const int*)  d_in[2];
    const float* E    = (const float*)d_in[3];
    const float* Uw   = (const float*)d_in[4];
    const float* Ubv  = (const float*)d_in[5];
    const float* Vw   = (const float*)d_in[6];
    const float* Vb   = (const float*)d_in[7];
    const float* Ww   = (const float*)d_in[8];
    const float* Wb   = (const float*)d_in[9];
    const float* sk   = (const float*)d_in[10];
    const float* Hw   = (const float*)d_in[11];
    const float* Hb   = (const float*)d_in[12];

    // workspace (float slots): sTb16 (1M bf16 = 512K floats) | WsT 1M | vkey 2560
    // | qv/a1v/a2v 3*8192 | h 163840 | SK 163840   (~7.7 MB total)
    float* ws    = (float*)d_ws;
    unsigned short* sTb16 = (unsigned short*)ws;
    float* WsT   = ws + 524288;
    float* vkey  = WsT + 1048576;
    float* qv    = vkey + 2560;
    float* a1v   = qv  + 8192;
    float* a2v   = a1v + 8192;
    float* h     = a2v + 8192;
    float* SK    = h   + 163840;

    prep_kernel<<<1108, 128, 0, stream>>>(ids, ques, ans, E, Ww, Wb, Vw, Vb, sk,
                                          sTb16, WsT, vkey, qv, a1v, a2v, SK);
    scan_kernel<<<20, 512, 0, stream>>>(sTb16, WsT, vkey, Uw, Ubv, SK, h);
    final_kernel<<<64, 128, 0, stream>>>(h, qv, a1v, a2v, Hw, Hb, (float*)d_out);
}

// Round 12
// 399.219 us; speedup vs baseline: 1.1255x; 1.1255x over previous
//
#include <hip/hip_runtime.h>
#include <math.h>

// EntNet forward on MI355X.
// Sizes: VOC=32000, MEM=128, NSLOTS=20, NSENT=128, MAXLEN=32, QLEN=16, ANSLEN=8, B=64
//
// R11 post-mortem (pipe-busy arithmetic): MFMA busy 1536 cyc/step and VALU busy
// 2109 both match static counts; R11 did LESS work than R10 yet was 1500 cyc
// slower -> cost = length of the serialized per-step dependency chain (gate
// rode as a dependent suffix of the MFMA chain: gacc 8-deep -> diag tree ->
// sigmoid -> update). R12 keeps R11's cheap parts (lane-owns-b column, 4xb64
// state writes, ping-pong single barrier, no g_l) and moves the gate OFF the
// chain: partials from fp32 register state at END of step t (lane owns 16 of
// row b's m-cells), published in transposed pg[pidx][b] (conflict-free);
// at top of t+1 each lane sums its 8 partials + sigmoid -> gate ready early,
// parallel to the 2x8-deep MFMA chains (16 MFMAs, gacc gone).
// Register model (R2/3/4/8): 512thr 1blk -> 256 regs/wave; this uses ~110+32.

typedef __attribute__((ext_vector_type(8)))  short bf16x8;
typedef __attribute__((ext_vector_type(16))) float f32x16;

__device__ __forceinline__ unsigned short f2bh(float x) {   // f32 -> bf16 RNE
    unsigned int u = __float_as_uint(x);
    u += 0x7FFFu + ((u >> 16) & 1u);
    return (unsigned short)(u >> 16);
}
__device__ __forceinline__ float bh2f(unsigned short h) {
    return __uint_as_float(((unsigned int)h) << 16);
}

// ---------------------------------------------------------------- prep
__global__ __launch_bounds__(128) void prep_kernel(
    const int* __restrict__ ids, const int* __restrict__ ques, const int* __restrict__ ans,
    const float* __restrict__ E, const float* __restrict__ Ww, const float* __restrict__ Wb,
    const float* __restrict__ Vw, const float* __restrict__ Vb, const float* __restrict__ skeys,
    unsigned short* __restrict__ sTb16, float* __restrict__ WsT, float* __restrict__ vkey,
    float* __restrict__ qv, float* __restrict__ a1v, float* __restrict__ a2v,
    float* __restrict__ SK)
{
    const int bi  = blockIdx.x;
    const int tid = threadIdx.x;   // 128
    __shared__ float s_l[8][132];
    __shared__ float sk_l[20 * 132];
    __shared__ float k_l[128];
    if (bi < 1024) {
        const int b = bi >> 4;
        const int g = bi & 15;
        for (int r = tid; r < 2560; r += 128) sk_l[(r >> 7) * 132 + (r & 127)] = skeys[r];
        for (int tt = 0; tt < 8; ++tt) {
            const int t     = g * 8 + tt;
            const int token = ids[b * 4096 + t];
            const float v   = E[token * 128 + tid];
            s_l[tt][tid] = v;
            sTb16[(t * 64 + b) * 128 + tid] = f2bh(v);   // bf16 plane, layout (t,b,m)
        }
        __syncthreads();
        // Ws rows
        float acc[8];
        const float wbn = Wb[tid];
        #pragma unroll
        for (int i = 0; i < 8; ++i) acc[i] = wbn;
        const float4* wrow = (const float4*)(Ww + tid * 128);
        for (int m4 = 0; m4 < 32; ++m4) {
            const float4 w = wrow[m4];
            #pragma unroll
            for (int tt = 0; tt < 8; ++tt) {
                acc[tt] += s_l[tt][m4*4+0]*w.x + s_l[tt][m4*4+1]*w.y
                         + s_l[tt][m4*4+2]*w.z + s_l[tt][m4*4+3]*w.w;
            }
        }
        for (int tt = 0; tt < 8; ++tt)
            WsT[((g*8+tt) * 64 + b) * 128 + tid] = acc[tt];     // layout (t, b, n)
        // SK[j][t][b] = dot(s_t[b], skeys[j])  (gate key-dot, hoisted from scan)
        for (int idx = tid; idx < 160; idx += 128) {
            const int tt = idx / 20;
            const int jj = idx - tt * 20;
            float d = 0.f;
            for (int m = 0; m < 128; ++m) d += s_l[tt][m] * sk_l[jj * 132 + m];
            SK[(jj * 128 + (g*8 + tt)) * 64 + b] = d;
        }
    } else if (bi < 1044) {
        const int j = bi - 1024;
        k_l[tid] = skeys[j * 128 + tid];
        __syncthreads();
        float acc = Vb[tid];
        const float4* vrow = (const float4*)(Vw + tid * 128);
        for (int m4 = 0; m4 < 32; ++m4) {
            const float4 w = vrow[m4];
            acc += k_l[m4*4]*w.x + k_l[m4*4+1]*w.y + k_l[m4*4+2]*w.z + k_l[m4*4+3]*w.w;
        }
        vkey[j * 128 + tid] = acc;
    } else {
        const int b = bi - 1044;
        float sq = 0.f, s1 = 0.f, s2 = 0.f;
        for (int i = 0; i < 16; ++i) sq += E[ques[b*16+i] * 128 + tid];
        for (int i = 0; i < 8;  ++i) s1 += E[ans[(b*8+i)*2+0] * 128 + tid];
        for (int i = 0; i < 8;  ++i) s2 += E[ans[(b*8+i)*2+1] * 128 + tid];
        qv [b*128+tid] = sq * (1.f/16.f);
        a1v[b*128+tid] = s1 * 0.125f;
        a2v[b*128+tid] = s2 * 0.125f;
    }
}

// ---------------------------------------------------------------- scan
// One block per slot j. 512 threads = 8 waves, 2 waves/SIMD.
// Wave = (bt2 = wave&1, nt2 = wave>>1). Owned C tile: C[n][b] (A=weight frag,
// B=state frag). Lane (l32, q): column b = bt2*32+l32, rows
// n(r) = nt2*32 + (r&3) + 8*(r>>2) + 4q  [C/D layout, m74/m101].
// State AB bf16 [2][64][136] ping-pong; fp32 recurrence xprev[16] in regs.
// Gate: partials pg[pidx][b] (pidx = nt2*2+q, transposed -> conflict-free)
// computed END of step t from xprev + s_{t+1} (4xb64 bf16 loads issued at top
// of step t); at top of t+1 each lane sums 8 partials + sigmoid lane-locally.
// ONE barrier per step.
__global__ __launch_bounds__(512, 1) void scan_kernel(
    const unsigned short* __restrict__ sTb16, const float* __restrict__ WsT,
    const float* __restrict__ vkey, const float* __restrict__ Uw,
    const float* __restrict__ Ub, const float* __restrict__ SK,
    float* __restrict__ h_out)
{
    __shared__ unsigned short AB[2][64 * 136];     // bf16 state, ping-pong
    __shared__ float pg[2][8 * 64];                // gate partials [pidx][b]
    __shared__ __align__(16) float wred[2][8];     // per-wave ssq, ping-pong

    const int j    = blockIdx.x;
    const int tid  = threadIdx.x;        // 512
    const int wave = tid >> 6;           // 0..7
    const int lane = tid & 63;
    const int l32  = lane & 31;
    const int q    = lane >> 5;          // 0..1
    const int bt2  = wave & 1;           // b tile
    const int nt2  = wave >> 1;          // n tile
    const int b    = bt2 * 32 + l32;     // owned batch column
    const int nw   = nt2 * 32 + l32;     // weight fragment row
    const int pidx = nt2 * 2 + q;        // gate-partial slot

    // ---- one-time: weight fragments (A operand) -> 64 VGPRs ----
    bf16x8 w_h[8], w_l[8];
    #pragma unroll
    for (int kc = 0; kc < 8; ++kc) {
        const float4* src = (const float4*)(Uw + nw*128 + kc*16 + q*8);
        const float4 v0 = src[0], v1 = src[1];
        const float xs[8] = {v0.x,v0.y,v0.z,v0.w, v1.x,v1.y,v1.z,v1.w};
        #pragma unroll
        for (int e = 0; e < 8; ++e) {
            const unsigned short h = f2bh(xs[e]);
            w_h[kc][e] = (short)h;
            w_l[kc][e] = (short)f2bh(xs[e] - bh2f(h));
        }
    }
    // ubv[r] = Ub[n(r)] + Vkey[j][n(r)]
    float ubv[16];
    #pragma unroll
    for (int r = 0; r < 16; ++r) {
        const int n = nt2*32 + (r & 3) + 8*(r >> 2) + 4*q;
        ubv[r] = Ub[n] + vkey[j*128 + n];
    }
    for (int i = tid; i < 64*136; i += 512) AB[0][i] = 0;
    pg[0][tid] = 0.f;                     // 512 slots, one per thread
    if (tid < 8) wred[0][tid] = 0.125f;   // sum = 1 -> inv_s = 1 (state = 0)

    float xprev[16];
    #pragma unroll
    for (int r = 0; r < 16; ++r) xprev[r] = 0.f;

    // ---- step-0 globals ----
    float wsv[16];
    float skv;
    {
        const float* wp = WsT + (0*64 + b)*128;
        #pragma unroll
        for (int g4 = 0; g4 < 4; ++g4) {
            const float4 w = *(const float4*)(wp + nt2*32 + 8*g4 + 4*q);
            wsv[g4*4+0]=w.x; wsv[g4*4+1]=w.y; wsv[g4*4+2]=w.z; wsv[g4*4+3]=w.w;
        }
        skv = SK[(j*128 + 0)*64 + b];
    }
    __syncthreads();

    for (int t = 0; t < 128; ++t) {
        const int cur = t & 1, nxt = cur ^ 1;
        const int tn  = (t < 127) ? t + 1 : 127;

        // ---- issue s_{t+1} gate loads early (used at END of this step) ----
        unsigned int sgv[8];   // 16 bf16 at n(r), 4 x b64
        {
            const unsigned short* sp = sTb16 + (tn*64 + b)*128 + nt2*32 + 4*q;
            #pragma unroll
            for (int g4 = 0; g4 < 4; ++g4) {
                const uint2 v = *(const uint2*)(sp + 8*g4);
                sgv[g4*2+0] = v.x; sgv[g4*2+1] = v.y;
            }
        }

        // ---- inv_s + gate (lane-local, off the MFMA chain) ----
        const float4 r0 = *(const float4*)(&wred[cur][0]);
        const float4 r1 = *(const float4*)(&wred[cur][4]);
        const float inv_s = 1.f / sqrtf(r0.x+r0.y+r0.z+r0.w + r1.x+r1.y+r1.z+r1.w);
        float dg = 0.f;
        #pragma unroll
        for (int p = 0; p < 8; ++p) dg += pg[cur][p*64 + b];
        const float gg = 1.f / (1.f + expf(-(inv_s * dg + skv)));

        // ---- state fragments (B operand) + MFMA: 2 planes, 2 indep chains ----
        const unsigned short* arow = &AB[cur][b*136 + q*8];
        bf16x8 a[8];
        #pragma unroll
        for (int kc = 0; kc < 8; ++kc) a[kc] = *(const bf16x8*)(arow + kc*16);
        f32x16 acc0 = {0.f,0.f,0.f,0.f,0.f,0.f,0.f,0.f,
                       0.f,0.f,0.f,0.f,0.f,0.f,0.f,0.f};
        f32x16 acc1 = acc0;
        #pragma unroll
        for (int kc = 0; kc < 8; ++kc) {
            if (kc & 1) {
                acc1 = __builtin_amdgcn_mfma_f32_32x32x16_bf16(w_h[kc], a[kc], acc1, 0, 0, 0);
                acc1 = __builtin_amdgcn_mfma_f32_32x32x16_bf16(w_l[kc], a[kc], acc1, 0, 0, 0);
            } else {
                acc0 = __builtin_amdgcn_mfma_f32_32x32x16_bf16(w_h[kc], a[kc], acc0, 0, 0, 0);
                acc0 = __builtin_amdgcn_mfma_f32_32x32x16_bf16(w_l[kc], a[kc], acc0, 0, 0, 0);
            }
        }

        // ---- update owned column: 4 quads of contiguous n ----
        unsigned short* wrow = &AB[nxt][b*136];
        float ssq = 0.f;
        #pragma unroll
        for (int g4 = 0; g4 < 4; ++g4) {
            float xs[4];
            #pragma unroll
            for (int e = 0; e < 4; ++e) {
                const int r = g4*4 + e;
                float hr = fmaf(inv_s, acc0[r] + acc1[r], ubv[r] + wsv[r]);
                hr = fmaxf(hr, 0.f);                       // h_cand
                const float x = fmaf(inv_s, xprev[r], gg * hr);
                xprev[r] = x;
                xs[e] = x;
                ssq = fmaf(x, x, ssq);
            }
            const unsigned int p0 = ((unsigned int)f2bh(xs[1]) << 16) | f2bh(xs[0]);
            const unsigned int p1 = ((unsigned int)f2bh(xs[3]) << 16) | f2bh(xs[2]);
            *(uint2*)(wrow + nt2*32 + 8*g4 + 4*q) = make_uint2(p0, p1);
        }

        // ---- gate partial for t+1 from fp32 register state ----
        {
            float part = 0.f;
            #pragma unroll
            for (int g4 = 0; g4 < 4; ++g4) {
                part = fmaf(__uint_as_float(sgv[g4*2+0] << 16),          xprev[g4*4+0], part);
                part = fmaf(__uint_as_float(sgv[g4*2+0] & 0xFFFF0000u), xprev[g4*4+1], part);
                part = fmaf(__uint_as_float(sgv[g4*2+1] << 16),          xprev[g4*4+2], part);
                part = fmaf(__uint_as_float(sgv[g4*2+1] & 0xFFFF0000u), xprev[g4*4+3], part);
            }
            pg[nxt][pidx*64 + b] = part;    // transposed: conflict-free
        }

        // ---- prefetch t+1 globals (R10-proven placement) ----
        {
            const float* wp = WsT + (tn*64 + b)*128;
            #pragma unroll
            for (int g4 = 0; g4 < 4; ++g4) {
                const float4 w = *(const float4*)(wp + nt2*32 + 8*g4 + 4*q);
                wsv[g4*4+0]=w.x; wsv[g4*4+1]=w.y; wsv[g4*4+2]=w.z; wsv[g4*4+3]=w.w;
            }
            skv = SK[(j*128 + tn)*64 + b];
        }

        // ---- block ssq -> wred[nxt] ----
        #pragma unroll
        for (int m = 1; m < 64; m <<= 1) ssq += __shfl_xor(ssq, m, 64);
        if (lane == 0) wred[nxt][wave] = ssq;
        __syncthreads();   // single barrier: AB/pg/wred [nxt] published
    }

    // ---- h = inv * state (fp32 path), layout (b, j, m) ----
    const float4 f0 = *(const float4*)(&wred[0][0]);
    const float4 f1 = *(const float4*)(&wred[0][4]);
    const float invf = 1.f / sqrtf(f0.x+f0.y+f0.z+f0.w + f1.x+f1.y+f1.z+f1.w);
    #pragma unroll
    for (int g4 = 0; g4 < 4; ++g4) {
        const float4 o = make_float4(invf*xprev[g4*4+0], invf*xprev[g4*4+1],
                                     invf*xprev[g4*4+2], invf*xprev[g4*4+3]);
        *(float4*)(h_out + (b*20 + j)*128 + nt2*32 + 8*g4 + 4*q) = o;
    }
}

// ---------------------------------------------------------------- final
__global__ __launch_bounds__(128) void final_kernel(
    const float* __restrict__ h, const float* __restrict__ qv,
    const float* __restrict__ a1v, const float* __restrict__ a2v,
    const float* __restrict__ Hw, const float* __restrict__ Hb,
    float* __restrict__ out)
{
    const int b   = blockIdx.x;
    const int tid = threadIdx.x;    // 128
    __shared__ float hb[20][128];
    __shared__ float ql[128];
    __shared__ float ul[128];
    __shared__ float pl[20];
    __shared__ float lgt[20];
    __shared__ float red1[2], red2[2];

    for (int jj = 0; jj < 20; ++jj) hb[jj][tid] = h[(b*20+jj)*128 + tid];
    ql[tid] = qv[b*128 + tid];
    __syncthreads();
    if (tid < 20) {
        float d = 0.f;
        for (int m = 0; m < 128; ++m) d += hb[tid][m] * ql[m];
        lgt[tid] = d;
    }
    __syncthreads();
    if (tid == 0) {
        float mx = lgt[0];
        for (int jj = 1; jj < 20; ++jj) mx = fmaxf(mx, lgt[jj]);
        float s = 0.f;
        for (int jj = 0; jj < 20; ++jj) { const float e = expf(lgt[jj]-mx); pl[jj] = e; s += e; }
        const float is = 1.f / s;
        for (int jj = 0; jj < 20; ++jj) pl[jj] *= is;
    }
    __syncthreads();
    float u = 0.f;
    for (int jj = 0; jj < 20; ++jj) u += pl[jj] * hb[jj][tid];
    ul[tid] = u;
    __syncthreads();
    float acc = ql[tid] + Hb[tid];
    const float4* hwr = (const float4*)(Hw + tid*128);
    for (int m4 = 0; m4 < 32; ++m4) {
        const float4 w = hwr[m4];
        acc += ul[m4*4]*w.x + ul[m4*4+1]*w.y + ul[m4*4+2]*w.z + ul[m4*4+3]*w.w;
    }
    const float r  = fmaxf(acc, 0.f);
    float y1 = r * a1v[b*128+tid];
    float y2 = r * a2v[b*128+tid];
    #pragma unroll
    for (int mask = 1; mask < 64; mask <<= 1) {
        y1 += __shfl_xor(y1, mask, 64);
        y2 += __shfl_xor(y2, mask, 64);
    }
    if ((tid & 63) == 0) { red1[tid>>6] = y1; red2[tid>>6] = y2; }
    __syncthreads();
    if (tid == 0) {
        const float z1 = red1[0] + red1[1];
        const float z2 = red2[0] + red2[1];
        const float mx = fmaxf(z1, z2);
        const float e1 = expf(z1-mx), e2 = expf(z2-mx);
        const float s  = e1 + e2;
        out[b*2+0] = e1 / s;
        out[b*2+1] = e2 / s;
    }
}

// ---------------------------------------------------------------- launch
extern "C" void kernel_launch(void* const* d_in, const int* in_sizes, int n_in,
                              void* d_out, int out_size, void* d_ws, size_t ws_size,
                              hipStream_t stream)
{
    const int*   ids  = (const int*)  d_in[0];
    const int*   ques = (const int*)  d_in[1];
    const int*   ans  = (const int*)  d_in[2];
    const float* E    = (const float*)d_in[3];
    const float* Uw   = (const float*)d_in[4];
    const float* Ubv  = (const float*)d_in[5];
    const float* Vw   = (const float*)d_in[6];
    const float* Vb   = (const float*)d_in[7];
    const float* Ww   = (const float*)d_in[8];
    const float* Wb   = (const float*)d_in[9];
    const float* sk   = (const float*)d_in[10];
    const float* Hw   = (const float*)d_in[11];
    const float* Hb   = (const float*)d_in[12];

    // workspace (float slots): sTb16 (1M bf16 = 512K floats) | WsT 1M | vkey 2560
    // | qv/a1v/a2v 3*8192 | h 163840 | SK 163840   (~7.7 MB total)
    float* ws    = (float*)d_ws;
    unsigned short* sTb16 = (unsigned short*)ws;
    float* WsT   = ws + 524288;
    float* vkey  = WsT + 1048576;
    float* qv    = vkey + 2560;
    float* a1v   = qv  + 8192;
    float* a2v   = a1v + 8192;
    float* h     = a2v + 8192;
    float* SK    = h   + 163840;

    prep_kernel<<<1108, 128, 0, stream>>>(ids, ques, ans, E, Ww, Wb, Vw, Vb, sk,
                                          sTb16, WsT, vkey, qv, a1v, a2v, SK);
    scan_kernel<<<20, 512, 0, stream>>>(sTb16, WsT, vkey, Uw, Ubv, SK, h);
    final_kernel<<<64, 128, 0, stream>>>(h, qv, a1v, a2v, Hw, Hb, (float*)d_out);
}

// Round 13
// 345.731 us; speedup vs baseline: 1.2996x; 1.1547x over previous
//
#include <hip/hip_runtime.h>
#include <math.h>

// EntNet forward on MI355X.
// Sizes: VOC=32000, MEM=128, NSLOTS=20, NSENT=128, MAXLEN=32, QLEN=16, ANSLEN=8, B=64
//
// History: R10 (bf16 state plane, fp32 register recurrence, 2 barriers) = 278us
// scan, best. R11 (diag-gate on MFMA chain) 357, R12 (off-chain gate, 1 barrier)
// 296 — three structures cluster at 5200-5600 cyc/step, all pipes <50%:
// latency plateau of the 20-CU barrier-synced recurrence. R13 = R10 byte-exact
// + ONE change: single-plane bf16 weights (drop w_l) -> 8 MFMAs in 2x4-deep
// chains, halved MFMA pipe time, -32 VGPRs. Precision cover: absmax 0.0 for 8
// rounds (output softmax saturated); 2^-8-relative matmul perturbation is far
// inside the 1.875e-2 budget.

typedef __attribute__((ext_vector_type(8)))  short bf16x8;
typedef __attribute__((ext_vector_type(16))) float f32x16;

__device__ __forceinline__ unsigned short f2bh(float x) {   // f32 -> bf16 RNE
    unsigned int u = __float_as_uint(x);
    u += 0x7FFFu + ((u >> 16) & 1u);
    return (unsigned short)(u >> 16);
}
__device__ __forceinline__ float bh2f(unsigned short h) {
    return __uint_as_float(((unsigned int)h) << 16);
}
// u32 holding two bf16 (little-endian): low 16 = element 2i, high = 2i+1
__device__ __forceinline__ float blo(unsigned int w) { return __uint_as_float(w << 16); }
__device__ __forceinline__ float bhi(unsigned int w) { return __uint_as_float(w & 0xFFFF0000u); }

// ---------------------------------------------------------------- prep
__global__ __launch_bounds__(128) void prep_kernel(
    const int* __restrict__ ids, const int* __restrict__ ques, const int* __restrict__ ans,
    const float* __restrict__ E, const float* __restrict__ Ww, const float* __restrict__ Wb,
    const float* __restrict__ Vw, const float* __restrict__ Vb, const float* __restrict__ skeys,
    float* __restrict__ sT, float* __restrict__ WsT, float* __restrict__ vkey,
    float* __restrict__ qv, float* __restrict__ a1v, float* __restrict__ a2v,
    float* __restrict__ SK)
{
    const int bi  = blockIdx.x;
    const int tid = threadIdx.x;   // 128
    __shared__ float s_l[8][132];
    __shared__ float sk_l[20 * 132];
    __shared__ float k_l[128];
    if (bi < 1024) {
        const int b = bi >> 4;
        const int g = bi & 15;
        for (int r = tid; r < 2560; r += 128) sk_l[(r >> 7) * 132 + (r & 127)] = skeys[r];
        for (int tt = 0; tt < 8; ++tt) {
            const int t     = g * 8 + tt;
            const int token = ids[b * 4096 + t];
            const float v   = E[token * 128 + tid];
            s_l[tt][tid] = v;
            sT[(t * 64 + b) * 128 + tid] = v;         // layout (t, b, m)
        }
        __syncthreads();
        // Ws rows
        float acc[8];
        const float wbn = Wb[tid];
        #pragma unroll
        for (int i = 0; i < 8; ++i) acc[i] = wbn;
        const float4* wrow = (const float4*)(Ww + tid * 128);
        for (int m4 = 0; m4 < 32; ++m4) {
            const float4 w = wrow[m4];
            #pragma unroll
            for (int tt = 0; tt < 8; ++tt) {
                acc[tt] += s_l[tt][m4*4+0]*w.x + s_l[tt][m4*4+1]*w.y
                         + s_l[tt][m4*4+2]*w.z + s_l[tt][m4*4+3]*w.w;
            }
        }
        for (int tt = 0; tt < 8; ++tt)
            WsT[((g*8+tt) * 64 + b) * 128 + tid] = acc[tt];     // layout (t, b, n)
        // SK[j][t][b] = dot(s_t[b], skeys[j])  (gate key-dot, hoisted from scan)
        for (int idx = tid; idx < 160; idx += 128) {
            const int tt = idx / 20;
            const int jj = idx - tt * 20;
            float d = 0.f;
            for (int m = 0; m < 128; ++m) d += s_l[tt][m] * sk_l[jj * 132 + m];
            SK[(jj * 128 + (g*8 + tt)) * 64 + b] = d;
        }
    } else if (bi < 1044) {
        const int j = bi - 1024;
        k_l[tid] = skeys[j * 128 + tid];
        __syncthreads();
        float acc = Vb[tid];
        const float4* vrow = (const float4*)(Vw + tid * 128);
        for (int m4 = 0; m4 < 32; ++m4) {
            const float4 w = vrow[m4];
            acc += k_l[m4*4]*w.x + k_l[m4*4+1]*w.y + k_l[m4*4+2]*w.z + k_l[m4*4+3]*w.w;
        }
        vkey[j * 128 + tid] = acc;
    } else {
        const int b = bi - 1044;
        float sq = 0.f, s1 = 0.f, s2 = 0.f;
        for (int i = 0; i < 16; ++i) sq += E[ques[b*16+i] * 128 + tid];
        for (int i = 0; i < 8;  ++i) s1 += E[ans[(b*8+i)*2+0] * 128 + tid];
        for (int i = 0; i < 8;  ++i) s2 += E[ans[(b*8+i)*2+1] * 128 + tid];
        qv [b*128+tid] = sq * (1.f/16.f);
        a1v[b*128+tid] = s1 * 0.125f;
        a2v[b*128+tid] = s2 * 0.125f;
    }
}

// ---------------------------------------------------------------- scan (MFMA 32x32, bf16 state)
// One block per slot j. 512 threads = 8 waves, 2 waves/SIMD (256 regs/wave).
// Each wave owns ONE 32x32 C tile (bt2 = wave&1, nt2 = wave>>1).
//   Weights b_h (bf16 RNE of Uw) in 32 VGPRs, loaded once. SINGLE plane (R13).
//   State AB: bf16[64][136] in LDS, fragment-ready (A-frag = 1 ds_read_b128/kc,
//     no perms). fp32 recurrence xprev[16] in registers carries full precision;
//     only the matmul/gate INPUT is rounded to bf16 each step.
//   1 MFMA/kc, 2 independent 4-deep chains by kc parity.
// C/D layout [m74/m101]: col = lane&31, row = (reg&3)+8*(reg>>2)+4*(lane>>5).
// Prefetch for t+1 in the update phase (R7/R10-proven placement). 2 barriers/step.
__global__ __launch_bounds__(512, 1) void scan_kernel(
    const float* __restrict__ sT, const float* __restrict__ WsT,
    const float* __restrict__ vkey, const float* __restrict__ Uw,
    const float* __restrict__ Ub, const float* __restrict__ SK,
    float* __restrict__ h_out)
{
    __shared__ unsigned short AB[64 * 136];   // bf16 state, stride 136 (272B rows)
    __shared__ float g_l[64];
    __shared__ float wred[8];

    const int j    = blockIdx.x;
    const int tid  = threadIdx.x;        // 512
    const int wave = tid >> 6;           // 0..7
    const int lane = tid & 63;
    const int l32  = lane & 31;
    const int q    = lane >> 5;          // 0..1
    const int bt2  = wave & 1;           // b half
    const int nt2  = wave >> 1;          // n quarter
    const int n    = nt2 * 32 + l32;     // owned output column
    const int gb   = tid >> 3;           // gate: batch row 0..63
    const int gm   = (tid & 7) * 16;     // gate: m-slice (16 bf16)

    // ---- one-time: weight fragments -> 32 VGPRs (single bf16 plane) ----
    bf16x8 b_h[8];
    {
        const int k0 = q * 8;
        #pragma unroll
        for (int kc = 0; kc < 8; ++kc) {
            const float4* src = (const float4*)(Uw + n * 128 + kc * 16 + k0);
            const float4 v0 = src[0], v1 = src[1];
            const float xs[8] = {v0.x,v0.y,v0.z,v0.w, v1.x,v1.y,v1.z,v1.w};
            #pragma unroll
            for (int e = 0; e < 8; ++e) b_h[kc][e] = (short)f2bh(xs[e]);
        }
    }
    for (int i = tid; i < 64 * 136 / 2; i += 512) ((unsigned int*)AB)[i] = 0u;
    const float ubv = Ub[n] + vkey[j * 128 + n];

    // fp32 recurrence state (C layout), registers across steps
    float xprev[16];
    #pragma unroll
    for (int r = 0; r < 16; ++r) xprev[r] = 0.f;

    // ---- current-step globals (t = 0) ----
    float4 sv0, sv1, sv2, sv3;
    float  skv;
    float  wsv[16];
    {
        const float4* s4 = (const float4*)(sT + (0*64 + gb)*128 + gm);
        sv0 = s4[0]; sv1 = s4[1]; sv2 = s4[2]; sv3 = s4[3];
        skv = SK[(j*128 + 0)*64 + gb];
        #pragma unroll
        for (int r = 0; r < 16; ++r) {
            const int brow = bt2*32 + 4*q + (r & 3) + 8*(r >> 2);
            wsv[r] = WsT[(0*64 + brow)*128 + n];
        }
    }
    __syncthreads();

    float inv_s = 1.f;                   // true mem = inv_s * bf16(state)

    for (int t = 0; t < 128; ++t) {
        // ---- gate: g[b] = sigmoid(inv*dot(s_t[b],U[b]) + SK[j][t][b]) ----
        {
            const uint4* u4 = (const uint4*)(AB + gb * 136 + gm);   // 272B rows: aligned
            const uint4 w0 = u4[0], w1 = u4[1];                     // 16 bf16
            float d1 = sv0.x*blo(w0.x) + sv0.y*bhi(w0.x)
                     + sv0.z*blo(w0.y) + sv0.w*bhi(w0.y)
                     + sv1.x*blo(w0.z) + sv1.y*bhi(w0.z)
                     + sv1.z*blo(w0.w) + sv1.w*bhi(w0.w)
                     + sv2.x*blo(w1.x) + sv2.y*bhi(w1.x)
                     + sv2.z*blo(w1.y) + sv2.w*bhi(w1.y)
                     + sv3.x*blo(w1.z) + sv3.y*bhi(w1.z)
                     + sv3.z*blo(w1.w) + sv3.w*bhi(w1.w);
            d1 += __shfl_xor(d1, 1, 64);
            d1 += __shfl_xor(d1, 2, 64);
            d1 += __shfl_xor(d1, 4, 64);
            if ((tid & 7) == 0) g_l[gb] = 1.f / (1.f + expf(-(inv_s * d1 + skv)));
        }

        // ---- MFMA: acc = U(32b x 128m) . W(32n x 128m)^T, 2x4-deep chains ----
        f32x16 acc0 = {0.f,0.f,0.f,0.f,0.f,0.f,0.f,0.f,
                       0.f,0.f,0.f,0.f,0.f,0.f,0.f,0.f};
        f32x16 acc1 = acc0;
        {
            const unsigned short* arow = AB + (bt2*32 + l32) * 136 + q * 8;
            #pragma unroll
            for (int kc = 0; kc < 8; ++kc) {
                const bf16x8 a = *(const bf16x8*)(arow + kc * 16);   // fragment-ready
                if (kc & 1) acc1 = __builtin_amdgcn_mfma_f32_32x32x16_bf16(a, b_h[kc], acc1, 0, 0, 0);
                else        acc0 = __builtin_amdgcn_mfma_f32_32x32x16_bf16(a, b_h[kc], acc0, 0, 0, 0);
            }
        }
        __syncthreads();   // B1: AB reads complete; g_l visible

        // ---- update owned (b, n) cells in C layout ----
        const float4 gA = *(const float4*)(g_l + bt2*32 + 4*q + 0);
        const float4 gB = *(const float4*)(g_l + bt2*32 + 4*q + 8);
        const float4 gC = *(const float4*)(g_l + bt2*32 + 4*q + 16);
        const float4 gD = *(const float4*)(g_l + bt2*32 + 4*q + 24);
        const float gr[16] = {gA.x,gA.y,gA.z,gA.w, gB.x,gB.y,gB.z,gB.w,
                              gC.x,gC.y,gC.z,gC.w, gD.x,gD.y,gD.z,gD.w};
        float ssq = 0.f;
        #pragma unroll
        for (int r = 0; r < 16; ++r) {
            const int brow = bt2*32 + 4*q + (r & 3) + 8*(r >> 2);
            float hr = fmaf(inv_s, acc0[r] + acc1[r], ubv + wsv[r]);
            hr = fmaxf(hr, 0.f);                          // h_cand
            const float x = fmaf(inv_s, xprev[r], gr[r] * hr);
            xprev[r] = x;                                 // fp32 recurrence
            AB[brow*136 + n] = f2bh(x);                   // bf16 matmul plane
            ssq = fmaf(x, x, ssq);
        }

        // ---- prefetch t+1 globals (R10 placement: overlaps shuffles + B2) ----
        {
            const int tn = (t < 127) ? t + 1 : 0;
            const float4* s4 = (const float4*)(sT + (tn*64 + gb)*128 + gm);
            sv0 = s4[0]; sv1 = s4[1]; sv2 = s4[2]; sv3 = s4[3];
            skv = SK[(j*128 + tn)*64 + gb];
            #pragma unroll
            for (int r = 0; r < 16; ++r) {
                const int brow = bt2*32 + 4*q + (r & 3) + 8*(r >> 2);
                wsv[r] = WsT[(tn*64 + brow)*128 + n];
            }
        }

        #pragma unroll
        for (int m = 1; m < 64; m <<= 1) ssq += __shfl_xor(ssq, m, 64);
        if (lane == 0) wred[wave] = ssq;
        __syncthreads();   // B2: AB writes + wred partials visible
        const float4 w0 = *(const float4*)(wred);
        const float4 w1 = *(const float4*)(wred + 4);
        inv_s = 1.f / sqrtf(w0.x+w0.y+w0.z+w0.w + w1.x+w1.y+w1.z+w1.w);
    }

    // ---- h = inv * state (fp32 path), layout (b, j, m) ----
    #pragma unroll
    for (int r = 0; r < 16; ++r) {
        const int brow = bt2*32 + 4*q + (r & 3) + 8*(r >> 2);
        h_out[(brow*20 + j)*128 + n] = inv_s * xprev[r];
    }
}

// ---------------------------------------------------------------- final
__global__ __launch_bounds__(128) void final_kernel(
    const float* __restrict__ h, const float* __restrict__ qv,
    const float* __restrict__ a1v, const float* __restrict__ a2v,
    const float* __restrict__ Hw, const float* __restrict__ Hb,
    float* __restrict__ out)
{
    const int b   = blockIdx.x;
    const int tid = threadIdx.x;    // 128
    __shared__ float hb[20][128];
    __shared__ float ql[128];
    __shared__ float ul[128];
    __shared__ float pl[20];
    __shared__ float lgt[20];
    __shared__ float red1[2], red2[2];

    for (int jj = 0; jj < 20; ++jj) hb[jj][tid] = h[(b*20+jj)*128 + tid];
    ql[tid] = qv[b*128 + tid];
    __syncthreads();
    if (tid < 20) {
        float d = 0.f;
        for (int m = 0; m < 128; ++m) d += hb[tid][m] * ql[m];
        lgt[tid] = d;
    }
    __syncthreads();
    if (tid == 0) {
        float mx = lgt[0];
        for (int jj = 1; jj < 20; ++jj) mx = fmaxf(mx, lgt[jj]);
        float s = 0.f;
        for (int jj = 0; jj < 20; ++jj) { const float e = expf(lgt[jj]-mx); pl[jj] = e; s += e; }
        const float is = 1.f / s;
        for (int jj = 0; jj < 20; ++jj) pl[jj] *= is;
    }
    __syncthreads();
    float u = 0.f;
    for (int jj = 0; jj < 20; ++jj) u += pl[jj] * hb[jj][tid];
    ul[tid] = u;
    __syncthreads();
    float acc = ql[tid] + Hb[tid];
    const float4* hwr = (const float4*)(Hw + tid*128);
    for (int m4 = 0; m4 < 32; ++m4) {
        const float4 w = hwr[m4];
        acc += ul[m4*4]*w.x + ul[m4*4+1]*w.y + ul[m4*4+2]*w.z + ul[m4*4+3]*w.w;
    }
    const float r  = fmaxf(acc, 0.f);
    float y1 = r * a1v[b*128+tid];
    float y2 = r * a2v[b*128+tid];
    #pragma unroll
    for (int mask = 1; mask < 64; mask <<= 1) {
        y1 += __shfl_xor(y1, mask, 64);
        y2 += __shfl_xor(y2, mask, 64);
    }
    if ((tid & 63) == 0) { red1[tid>>6] = y1; red2[tid>>6] = y2; }
    __syncthreads();
    if (tid == 0) {
        const float z1 = red1[0] + red1[1];
        const float z2 = red2[0] + red2[1];
        const float mx = fmaxf(z1, z2);
        const float e1 = expf(z1-mx), e2 = expf(z2-mx);
        const float s  = e1 + e2;
        out[b*2+0] = e1 / s;
        out[b*2+1] = e2 / s;
    }
}

// ---------------------------------------------------------------- launch
extern "C" void kernel_launch(void* const* d_in, const int* in_sizes, int n_in,
                              void* d_out, int out_size, void* d_ws, size_t ws_size,
                              hipStream_t stream)
{
    const int*   ids  = (const int*)  d_in[0];
    const int*   ques = (const int*)  d_in[1];
    const int*   ans  = (const int*)  d_in[2];
    const float* E    = (const float*)d_in[3];
    const float* Uw   = (const float*)d_in[4];
    const float* Ubv  = (const float*)d_in[5];
    const float* Vw   = (const float*)d_in[6];
    const float* Vb   = (const float*)d_in[7];
    const float* Ww   = (const float*)d_in[8];
    const float* Wb   = (const float*)d_in[9];
    const float* sk   = (const float*)d_in[10];
    const float* Hw   = (const float*)d_in[11];
    const float* Hb   = (const float*)d_in[12];

    // workspace (floats): sT 1M | WsT 1M | vkey 2560 | qv/a1v/a2v 3*8192 | h 163840 | SK 163840
    float* ws   = (float*)d_ws;
    float* sT   = ws;
    float* WsT  = sT  + 1048576;
    float* vkey = WsT + 1048576;
    float* qv   = vkey + 2560;
    float* a1v  = qv  + 8192;
    float* a2v  = a1v + 8192;
    float* h    = a2v + 8192;
    float* SK   = h   + 163840;

    prep_kernel<<<1108, 128, 0, stream>>>(ids, ques, ans, E, Ww, Wb, Vw, Vb, sk,
                                          sT, WsT, vkey, qv, a1v, a2v, SK);
    scan_kernel<<<20, 512, 0, stream>>>(sT, WsT, vkey, Uw, Ubv, SK, h);
    final_kernel<<<64, 128, 0, stream>>>(h, qv, a1v, a2v, Hw, Hb, (float*)d_out);
}